// Round 5
// baseline (1112.103 us; speedup 1.0000x reference)
//
#include <hip/hip_runtime.h>
#include <stdint.h>

typedef unsigned short u16;
typedef unsigned int u32;
typedef __attribute__((ext_vector_type(8))) short short8;   // 8 bf16 (4 VGPR)
typedef __attribute__((ext_vector_type(4))) float f32x4;

#define NTHR 384
#define K2E16 0.09016844005556021f   /* log2(e)/16 : 1/sqrt(256) folded into exp2 */

// LDS map: kwL [96][304B] (29184) overlaid by fragL (49152); bvo f32[256]
#define KW_STRIDE 304
#define BVO_OFF   49152
#define LDS_TOTAL 50176

static __device__ __forceinline__ u16 f2bf(float f) {
  union { float f; u32 u; } v; v.f = f;
  u32 r = v.u + 0x7FFFu + ((v.u >> 16) & 1u);   // RNE
  return (u16)(r >> 16);
}
static __device__ __forceinline__ float bf2f(u16 x) {
  union { u32 u; float f; } v; v.u = ((u32)x) << 16; return v.f;
}

// ---------------------------------------------------------------------------
// K0: weight prep.
//  - WkqE[de][c]: c<128 -> sum_h Wk[de][h]*Wq[c][h]; c==128 -> Wk[de]·bq;
//                 c in 129..143 -> 0. bf16 MFMA B-frags (K=128, 9 col-tiles).
//    (bk-dependent score terms are constant over p -> cancel in softmax.)
//  - WvoF = bf16 B-frags of Wv@Wo (K=256, 16 col-tiles); bvo = bv@Wo + bo.
// ---------------------------------------------------------------------------
__global__ __launch_bounds__(256) void k_setup(
    const float* __restrict__ Wq, const float* __restrict__ Wk,
    const float* __restrict__ Wv, const float* __restrict__ Wo,
    const float* __restrict__ bq,
    const float* __restrict__ bv, const float* __restrict__ bo,
    u16* __restrict__ WkqF, u16* __restrict__ WvoF, float* __restrict__ bvo) {
  const int ci = blockIdx.x;   // k-row
  const int co = threadIdx.x;  // col
  float acc = 0.f;
  for (int h = 0; h < 256; ++h) acc += Wv[ci*256 + h] * Wo[h*256 + co];
  const int idxv = (((ci>>5)*16 + (co>>4))*64 + (((ci>>3)&3)*16 + (co&15)))*8 + (ci&7);
  WvoF[idxv] = f2bf(acc);
  if (ci < 128 && co < 144) {
    float a = 0.f;
    if (co < 128)       { for (int h = 0; h < 256; ++h) a += Wk[ci*256 + h] * Wq[co*256 + h]; }
    else if (co == 128) { for (int h = 0; h < 256; ++h) a += Wk[ci*256 + h] * bq[h]; }
    const int idx = (((ci>>5)*9 + (co>>4))*64 + (((ci>>3)&3)*16 + (co&15)))*8 + (ci&7);
    WkqF[idx] = f2bf(a);
  }
  if (ci == 0) {
    float a2 = 0.f;
    for (int h = 0; h < 256; ++h) a2 += bv[h] * Wo[h*256 + co];
    bvo[co] = a2 + bo[co];
  }
}

// ---------------------------------------------------------------------------
// K2 fused, grid (1024, 8), 6 waves, 50176B LDS (>=2 blocks/CU):
// M-partition: wave w owns rows [16w,16w+16) of every per-(b,n) matrix.
//   P1: KW = bf16(senc_rows)@WkqE -> kwL   (A-frags DIRECT from global)
//   P2: scoresT = KW[:,0:128]@sdecT (+ col128), softmax, af (1/sum folded)
//       (enc A-frag loads issued before P2, land during it)
//   P2b: enc2 = bf16(enc_rows)@Wvo -> acc2[16] in regs
//   P5: acc2 -> sigma-matched B-frags in fragL (overlays kwL)
//   P6: out = attn@enc2 + bvo
// ---------------------------------------------------------------------------
__global__ __launch_bounds__(NTHR, 4) void k_attn(
    const float* __restrict__ sdec, const float* __restrict__ senc,
    const float* __restrict__ enc,
    const u16* __restrict__ WkqF, const u16* __restrict__ WvoF,
    const float* __restrict__ bvo, float* __restrict__ out) {
  extern __shared__ char smem[];
  char* kwL   = smem;                  // 29184 B, dead after P2
  char* fragL = smem;                  // 49152 B, live P5..P6
  float* bvoL = (float*)(smem + BVO_OFF);

  const int n = blockIdx.x, b = blockIdx.y;
  const int tid = threadIdx.x, wave = tid >> 6, lane = tid & 63;
  const int g = lane >> 4, c15 = lane & 15;
  const int prow = 16*wave + c15;      // this wave's A-fragment row

  // ---- issue sdec + senc fragment loads (wave-own rows; deep, independent) ----
  const float* sdp = sdec + ((size_t)((b*96 + prow)*1024 + n))*128 + 8*g;
  const float* sep = senc + ((size_t)((b*96 + prow)*1024 + n))*128 + 8*g;
  float4 sdv[4][2], sev[4][2];
  #pragma unroll
  for (int kt = 0; kt < 4; ++kt) {
    sev[kt][0] = *(const float4*)(sep + 32*kt);
    sev[kt][1] = *(const float4*)(sep + 32*kt + 4);
    sdv[kt][0] = *(const float4*)(sdp + 32*kt);
    sdv[kt][1] = *(const float4*)(sdp + 32*kt + 4);
  }
  if (tid < 256) bvoL[tid] = bvo[tid];

  // senc -> bf16 A-frags
  short8 sef[4];
  #pragma unroll
  for (int kt = 0; kt < 4; ++kt) {
    union { u32 u[4]; short8 v; } cv;
    cv.u[0] = (u32)f2bf(sev[kt][0].x) | ((u32)f2bf(sev[kt][0].y) << 16);
    cv.u[1] = (u32)f2bf(sev[kt][0].z) | ((u32)f2bf(sev[kt][0].w) << 16);
    cv.u[2] = (u32)f2bf(sev[kt][1].x) | ((u32)f2bf(sev[kt][1].y) << 16);
    cv.u[3] = (u32)f2bf(sev[kt][1].z) | ((u32)f2bf(sev[kt][1].w) << 16);
    sef[kt] = cv.v;
  }

  // ---- P1: KW rows [16w,16w+16) x 144 = senc_rows @ WkqE ----
  f32x4 acc[9];
  #pragma unroll
  for (int nt = 0; nt < 9; ++nt) acc[nt] = (f32x4)0.f;
  #pragma unroll
  for (int kt = 0; kt < 4; ++kt) {
    #pragma unroll
    for (int nt = 0; nt < 9; ++nt) {
      const short8 bf = *(const short8*)(WkqF + (size_t)((kt*9 + nt)*64 + lane)*8);
      acc[nt] = __builtin_amdgcn_mfma_f32_16x16x32_bf16(sef[kt], bf, acc[nt], 0, 0, 0);
    }
  }
  // sdec -> bf16 B-frags (frees sdv)
  short8 sdf[4];
  #pragma unroll
  for (int kt = 0; kt < 4; ++kt) {
    union { u32 u[4]; short8 v; } cv;
    cv.u[0] = (u32)f2bf(sdv[kt][0].x) | ((u32)f2bf(sdv[kt][0].y) << 16);
    cv.u[1] = (u32)f2bf(sdv[kt][0].z) | ((u32)f2bf(sdv[kt][0].w) << 16);
    cv.u[2] = (u32)f2bf(sdv[kt][1].x) | ((u32)f2bf(sdv[kt][1].y) << 16);
    cv.u[3] = (u32)f2bf(sdv[kt][1].z) | ((u32)f2bf(sdv[kt][1].w) << 16);
    sdf[kt] = cv.v;
  }
  // KW epilogue: row p = 16w + 4g + r, col = c15 + 16nt
  #pragma unroll
  for (int nt = 0; nt < 9; ++nt) {
    #pragma unroll
    for (int r = 0; r < 4; ++r)
      *(u16*)(kwL + (16*wave + 4*g + r)*KW_STRIDE + 2*(c15 + 16*nt)) = f2bf(acc[nt][r]);
  }
  __syncthreads();   // bar#1: kwL complete

  // ---- issue enc fragment loads (land during scores/softmax) ----
  const float* ep = enc + ((size_t)((b*96 + prow)*1024 + n))*256 + 8*g;
  float4 ev[8][2];
  #pragma unroll
  for (int kt = 0; kt < 8; ++kt) {
    ev[kt][0] = *(const float4*)(ep + 32*kt);
    ev[kt][1] = *(const float4*)(ep + 32*kt + 4);
  }

  // ---- P2: scoresT = KW[:,0:128] @ sdecT for this wave's 16 q-cols ----
  f32x4 sac[6];
  #pragma unroll
  for (int pt = 0; pt < 6; ++pt) sac[pt] = (f32x4)0.f;
  #pragma unroll
  for (int kt = 0; kt < 4; ++kt) {
    #pragma unroll
    for (int pt = 0; pt < 6; ++pt) {
      const short8 kf = *(const short8*)(kwL + (16*pt + c15)*KW_STRIDE + 16*g + 64*kt);
      sac[pt] = __builtin_amdgcn_mfma_f32_16x16x32_bf16(kf, sdf[kt], sac[pt], 0, 0, 0);
    }
  }
  // + p-varying bias column (senc·(Wk·bq))
  #pragma unroll
  for (int pt = 0; pt < 6; ++pt)
    #pragma unroll
    for (int r = 0; r < 4; ++r)
      sac[pt][r] += bf2f(*(const u16*)(kwL + (16*pt + 4*g + r)*KW_STRIDE + 256));

  // ---- softmax over p; q = 16w + c15 lives in lanes {l, l^16, l^32} ----
  float m = sac[0][0];
  #pragma unroll
  for (int pt = 0; pt < 6; ++pt)
    #pragma unroll
    for (int r = 0; r < 4; ++r) m = fmaxf(m, sac[pt][r]);
  m = fmaxf(m, __shfl_xor(m, 16));
  m = fmaxf(m, __shfl_xor(m, 32));
  float s = 0.f;
  #pragma unroll
  for (int pt = 0; pt < 6; ++pt)
    #pragma unroll
    for (int r = 0; r < 4; ++r) {
      const float e = exp2f((sac[pt][r] - m) * K2E16);
      sac[pt][r] = e; s += e;
    }
  s += __shfl_xor(s, 16);
  s += __shfl_xor(s, 32);
  const float rs = 1.f / s;

  short8 af[3];
  #pragma unroll
  for (int kb = 0; kb < 3; ++kb) {
    union { u32 u[4]; short8 v; } cv;
    cv.u[0] = (u32)f2bf(sac[2*kb][0]*rs)   | ((u32)f2bf(sac[2*kb][1]*rs)   << 16);
    cv.u[1] = (u32)f2bf(sac[2*kb][2]*rs)   | ((u32)f2bf(sac[2*kb][3]*rs)   << 16);
    cv.u[2] = (u32)f2bf(sac[2*kb+1][0]*rs) | ((u32)f2bf(sac[2*kb+1][1]*rs) << 16);
    cv.u[3] = (u32)f2bf(sac[2*kb+1][2]*rs) | ((u32)f2bf(sac[2*kb+1][3]*rs) << 16);
    af[kb] = cv.v;
  }

  // enc -> bf16 A-frags (frees ev)
  short8 aef[8];
  #pragma unroll
  for (int kt = 0; kt < 8; ++kt) {
    union { u32 u[4]; short8 v; } cv;
    cv.u[0] = (u32)f2bf(ev[kt][0].x) | ((u32)f2bf(ev[kt][0].y) << 16);
    cv.u[1] = (u32)f2bf(ev[kt][0].z) | ((u32)f2bf(ev[kt][0].w) << 16);
    cv.u[2] = (u32)f2bf(ev[kt][1].x) | ((u32)f2bf(ev[kt][1].y) << 16);
    cv.u[3] = (u32)f2bf(ev[kt][1].z) | ((u32)f2bf(ev[kt][1].w) << 16);
    aef[kt] = cv.v;
  }

  // ---- P2b: enc2 rows [16w,16w+16) x 256 = enc_rows @ Wvo ----
  f32x4 acc2[16];
  #pragma unroll
  for (int nt = 0; nt < 16; ++nt) acc2[nt] = (f32x4)0.f;
  #pragma unroll
  for (int kt = 0; kt < 8; ++kt) {
    #pragma unroll
    for (int nt = 0; nt < 16; ++nt) {
      const short8 bf = *(const short8*)(WvoF + (size_t)((kt*16 + nt)*64 + lane)*8);
      acc2[nt] = __builtin_amdgcn_mfma_f32_16x16x32_bf16(aef[kt], bf, acc2[nt], 0, 0, 0);
    }
  }
  __syncthreads();   // bar#2: all kwL reads done -> fragL region writable

  // ---- P5: acc2 -> sigma-matched B-frags (kb = w>>1, e-half = w&1) ----
  {
    const int kb0 = wave >> 1, hi = wave & 1;
    #pragma unroll
    for (int nt = 0; nt < 16; ++nt) {
      uint2 o;
      o.x = (u32)f2bf(acc2[nt][0]) | ((u32)f2bf(acc2[nt][1]) << 16);
      o.y = (u32)f2bf(acc2[nt][2]) | ((u32)f2bf(acc2[nt][3]) << 16);
      *(uint2*)(fragL + (((nt*3 + kb0)*64 + lane) << 4) + hi*8) = o;
    }
  }
  __syncthreads();   // bar#3: fragL complete

  // ---- P6: out = attn @ enc2 + bvo; f32 store ----
  #pragma unroll
  for (int nt = 0; nt < 16; ++nt) {
    f32x4 oa = (f32x4)0.f;
    #pragma unroll
    for (int kb = 0; kb < 3; ++kb) {
      const short8 ef = *(const short8*)(fragL + (((nt*3 + kb)*64 + lane) << 4));
      oa = __builtin_amdgcn_mfma_f32_16x16x32_bf16(af[kb], ef, oa, 0, 0, 0);
    }
    const int c = c15 + 16*nt;
    const float bz = bvoL[c];
    #pragma unroll
    for (int r = 0; r < 4; ++r) {
      const int qi = 16*wave + 4*g + r;
      out[((size_t)((b*96 + qi)*1024 + n))*256 + c] = oa[r] + bz;
    }
  }
}

// ---------------------------------------------------------------------------
extern "C" void kernel_launch(void* const* d_in, const int* in_sizes, int n_in,
                              void* d_out, int out_size, void* d_ws, size_t ws_size,
                              hipStream_t stream) {
  const float* enc     = (const float*)d_in[0];
  const float* ste_enc = (const float*)d_in[1];
  const float* ste_dec = (const float*)d_in[2];
  const float* Wq = (const float*)d_in[3];
  const float* bq = (const float*)d_in[4];
  const float* Wk = (const float*)d_in[5];
  const float* bv = (const float*)d_in[8];
  const float* Wv = (const float*)d_in[7];
  const float* Wo = (const float*)d_in[9];
  const float* bo = (const float*)d_in[10];
  float* out = (float*)d_out;

  u16*   WkqF = (u16*)d_ws;                               // 36864 B
  u16*   WvoF = (u16*)((char*)d_ws + 36864);              // 131072 B -> 167936
  float* bvo  = (float*)((char*)d_ws + 167936);           // 1024 B

  k_setup<<<dim3(256), dim3(256), 0, stream>>>(Wq, Wk, Wv, Wo, bq, bv, bo,
                                               WkqF, WvoF, bvo);
  k_attn<<<dim3(1024, 8), dim3(NTHR), LDS_TOTAL, stream>>>(
      ste_dec, ste_enc, enc, WkqF, WvoF, bvo, out);
}